// Round 2
// baseline (88.387 us; speedup 1.0000x reference)
//
#include <hip/hip_runtime.h>
#include <math.h>

#define MARGIN 1.0f
#define NI 16        // i's register-blocked per pair-kernel block
#define BMAX 8192    // problem size (setup_inputs: B=8192, P=16); assumes B <= BMAX

struct Ctl {
    double sacc;
    double cacc;
    unsigned ticket;
    unsigned pad;
};

// ---------------- Kernel 1: per-row distance + accumulator init ----------------
__global__ __launch_bounds__(256) void dist_init_kernel(
    const float* __restrict__ pv,   // (B, P)
    const float* __restrict__ pt,   // (P,)
    float* __restrict__ dist,       // (B,)
    Ctl* __restrict__ ctl,
    int B, int P)
{
    int i = blockIdx.x * 256 + threadIdx.x;
    if (i == 0) { ctl->sacc = 0.0; ctl->cacc = 0.0; ctl->ticket = 0u; }
    if (i >= B) return;
    const float* row = pv + (size_t)i * P;
    float s = 0.f;
    if (P == 16) {
        const float4* r4 = (const float4*)row;
        const float4* t4 = (const float4*)pt;
        #pragma unroll
        for (int q = 0; q < 4; ++q) {
            float4 r = r4[q], t = t4[q];
            float d0 = r.x - t.x; s = fmaf(d0, d0, s);
            float d1 = r.y - t.y; s = fmaf(d1, d1, s);
            float d2 = r.z - t.z; s = fmaf(d2, d2, s);
            float d3 = r.w - t.w; s = fmaf(d3, d3, s);
        }
    } else {
        for (int p = 0; p < P; ++p) { float d = row[p] - pt[p]; s = fmaf(d, d, s); }
    }
    dist[i] = sqrtf(s);
}

// ---------------- Kernel 2: all-pairs loss, fused finalize ----------------
// Hot loop is pure VALU: per pair {v_cmp, v_sub, v_max, v_cndmask, v_add, v_addc}.
// No convergent intrinsics, no runtime-indexed arrays (spill-proof by construction).
__global__ __launch_bounds__(256) void pair_fused_kernel(
    const float* __restrict__ e,     // (B,) energies flat
    const float* __restrict__ dist,  // (B,)
    Ctl* __restrict__ ctl,
    float* __restrict__ out,
    int B, int nblocks)
{
    __shared__ float sd[BMAX];   // 32 KB
    __shared__ float se[BMAX];   // 32 KB -> 64 KB total, 2 blocks/CU
    const int tid = threadIdx.x;

    // stage full dist/e arrays once (vectorized); pad with -inf (never di<dj)
    {
        const int n4 = B >> 2;
        const float4* d4 = (const float4*)dist;
        const float4* e4 = (const float4*)e;
        float4* sd4 = (float4*)sd;
        float4* se4 = (float4*)se;
        for (int k = tid; k < n4; k += 256) { sd4[k] = d4[k]; se4[k] = e4[k]; }
        for (int k = (n4 << 2) + tid; k < B; k += 256) { sd[k] = dist[k]; se[k] = e[k]; }
        for (int k = B + tid; k < BMAX; k += 256) { sd[k] = -INFINITY; se[k] = 0.f; }
    }
    __syncthreads();

    // register-block this block's NI i's (wave-uniform broadcast reads)
    const int i0 = blockIdx.x * NI;
    float di[NI], ai[NI];
    #pragma unroll
    for (int ii = 0; ii < NI; ++ii) {
        const bool iok = (i0 + ii) < B;
        di[ii] = iok ? sd[i0 + ii] : INFINITY;          // +inf: mask never true
        ai[ii] = iok ? (se[i0 + ii] + MARGIN) : 0.f;
    }

    // 4 independent sum chains + 4 independent count chains (ILP, exact: cnt<=512)
    float s0 = 0.f, s1 = 0.f, s2 = 0.f, s3 = 0.f;
    unsigned c0 = 0u, c1 = 0u, c2 = 0u, c3 = 0u;

    for (int s = 0; s < (BMAX / 256); ++s) {
        const int j = (s << 8) + tid;
        const float dj = sd[j];   // 2-way bank alias across 64 lanes: free
        const float ej = se[j];
        #pragma unroll
        for (int ii = 0; ii < NI; ii += 4) {
            { const bool m = di[ii]   < dj; const float t = fmaxf(ai[ii]   - ej, 0.f); s0 += m ? t : 0.f; c0 += (unsigned)m; }
            { const bool m = di[ii+1] < dj; const float t = fmaxf(ai[ii+1] - ej, 0.f); s1 += m ? t : 0.f; c1 += (unsigned)m; }
            { const bool m = di[ii+2] < dj; const float t = fmaxf(ai[ii+2] - ej, 0.f); s2 += m ? t : 0.f; c2 += (unsigned)m; }
            { const bool m = di[ii+3] < dj; const float t = fmaxf(ai[ii+3] - ej, 0.f); s3 += m ? t : 0.f; c3 += (unsigned)m; }
        }
    }

    // wave reduce
    float sum = (s0 + s1) + (s2 + s3);
    float cnt = (float)((c0 + c1) + (c2 + c3));   // <=512*... per thread 512 max, exact
    #pragma unroll
    for (int o = 32; o > 0; o >>= 1) {
        sum += __shfl_xor(sum, o);
        cnt += __shfl_xor(cnt, o);
    }

    // cross-wave reduce: reuse sd/se (all reads done)
    __syncthreads();
    const int wid = tid >> 6;
    if ((tid & 63) == 0) { sd[wid] = sum; se[wid] = cnt; }
    __syncthreads();

    if (tid == 0) {
        double S = ((double)sd[0] + (double)sd[1]) + ((double)sd[2] + (double)sd[3]);
        double C = ((double)se[0] + (double)se[1]) + ((double)se[2] + (double)se[3]);
        atomicAdd(&ctl->sacc, S);
        atomicAdd(&ctl->cacc, C);
        __threadfence();
        unsigned t = atomicAdd(&ctl->ticket, 1u);
        if (t == (unsigned)(nblocks - 1)) {
            double fs = atomicAdd(&ctl->sacc, 0.0);   // coherent-point read
            double fc = atomicAdd(&ctl->cacc, 0.0);
            if (fc < 1.0) fc = 1.0;
            out[0] = (float)(fs / fc);
        }
    }
}

extern "C" void kernel_launch(void* const* d_in, const int* in_sizes, int n_in,
                              void* d_out, int out_size, void* d_ws, size_t ws_size,
                              hipStream_t stream)
{
    const float* energies = (const float*)d_in[0];  // (B,1) flat = B floats
    const float* pv       = (const float*)d_in[1];  // (B,P)
    const float* pt       = (const float*)d_in[2];  // (P,)
    int B = in_sizes[0];
    int P = in_sizes[2];

    float* dist = (float*)d_ws;
    size_t coff = (((size_t)BMAX * sizeof(float)) + 255) & ~(size_t)255;
    Ctl* ctl = (Ctl*)((char*)d_ws + coff);

    int nblocks = (B + NI - 1) / NI;   // 512 for B=8192 -> exactly 2 blocks/CU

    dist_init_kernel<<<(B + 255) / 256, 256, 0, stream>>>(pv, pt, dist, ctl, B, P);
    pair_fused_kernel<<<nblocks, 256, 0, stream>>>(energies, dist, ctl, (float*)d_out, B, nblocks);
}

// Round 3
// 71.171 us; speedup vs baseline: 1.2419x; 1.2419x over previous
//
#include <hip/hip_runtime.h>
#include <math.h>

#define MARGIN 1.0f
#define NI 16   // i's per pair-kernel block (register-blocked, wave-uniform)

// ---------------- Kernel A: per-row distance ----------------
__global__ __launch_bounds__(256) void dist_kernel(
    const float* __restrict__ pv,   // (B, P)
    const float* __restrict__ pt,   // (P,)
    float* __restrict__ dist,       // (B,)
    int B, int P)
{
    int i = blockIdx.x * 256 + threadIdx.x;
    if (i >= B) return;
    const float* row = pv + (size_t)i * P;
    float s = 0.f;
    if (P == 16) {
        const float4* r4 = (const float4*)row;
        const float4* t4 = (const float4*)pt;
        #pragma unroll
        for (int q = 0; q < 4; ++q) {
            float4 r = r4[q], t = t4[q];
            float d0 = r.x - t.x; s = fmaf(d0, d0, s);
            float d1 = r.y - t.y; s = fmaf(d1, d1, s);
            float d2 = r.z - t.z; s = fmaf(d2, d2, s);
            float d3 = r.w - t.w; s = fmaf(d3, d3, s);
        }
    } else {
        for (int p = 0; p < P; ++p) { float d = row[p] - pt[p]; s = fmaf(d, d, s); }
    }
    dist[i] = sqrtf(s);
}

// ---------------- Kernel B: all-pairs masked loss ----------------
// Per block: NI i's in registers (wave-uniform scalar loads). Each thread walks
// coalesced float4 j's straight from global (arrays are 32 KB each -> L2-resident
// on every XCD after first touch). Hot loop is pure VALU, no LDS, no atomics.
__global__ __launch_bounds__(256) void pair_kernel(
    const float* __restrict__ e,     // (B,)
    const float* __restrict__ dist,  // (B,)
    float* __restrict__ psum,        // (nblk,)
    float* __restrict__ pcnt,        // (nblk,)
    int B)
{
    const int tid = threadIdx.x;
    const int i0 = blockIdx.x * NI;

    float di[NI], ai[NI];
    #pragma unroll
    for (int ii = 0; ii < NI; ++ii) {
        const int i = i0 + ii;
        const bool iok = i < B;
        di[ii] = iok ? dist[i] : INFINITY;        // +inf: mask never true
        ai[ii] = iok ? (e[i] + MARGIN) : 0.f;
    }

    // 4 independent sum chains + 4 count chains (counts exact: <= 131072/block)
    float s0 = 0.f, s1 = 0.f, s2 = 0.f, s3 = 0.f;
    unsigned c0 = 0u, c1 = 0u, c2 = 0u, c3 = 0u;

    auto proc = [&](float dj, float ej) {
        #pragma unroll
        for (int ii = 0; ii < NI; ii += 4) {
            { const bool m = di[ii]   < dj; const float t = fmaxf(ai[ii]   - ej, 0.f); s0 += m ? t : 0.f; c0 += (unsigned)m; }
            { const bool m = di[ii+1] < dj; const float t = fmaxf(ai[ii+1] - ej, 0.f); s1 += m ? t : 0.f; c1 += (unsigned)m; }
            { const bool m = di[ii+2] < dj; const float t = fmaxf(ai[ii+2] - ej, 0.f); s2 += m ? t : 0.f; c2 += (unsigned)m; }
            { const bool m = di[ii+3] < dj; const float t = fmaxf(ai[ii+3] - ej, 0.f); s3 += m ? t : 0.f; c3 += (unsigned)m; }
        }
    };

    const int nvec = B >> 2;
    const float4* d4 = (const float4*)dist;
    const float4* e4 = (const float4*)e;

    // full rounds (all 256 threads in-bounds), one-iteration manual prefetch
    const int nfull = nvec >> 8;                 // nvec/256; 8 for B=8192
    float4 dc, ec;
    if (nfull > 0) { dc = d4[tid]; ec = e4[tid]; }
    for (int s = 0; s < nfull; ++s) {
        float4 dn, en;
        const bool more = (s + 1) < nfull;
        const int jn = ((s + 1) << 8) + tid;
        if (more) { dn = d4[jn]; en = e4[jn]; }
        proc(dc.x, ec.x);
        proc(dc.y, ec.y);
        proc(dc.z, ec.z);
        proc(dc.w, ec.w);
        if (more) { dc = dn; ec = en; }
    }
    // vector remainder (general B)
    for (int j4 = (nfull << 8) + tid; j4 < nvec; j4 += 256) {
        const float4 dv = d4[j4], ev = e4[j4];
        proc(dv.x, ev.x); proc(dv.y, ev.y); proc(dv.z, ev.z); proc(dv.w, ev.w);
    }
    // scalar remainder (general B)
    for (int j = (nvec << 2) + tid; j < B; j += 256) {
        proc(dist[j], e[j]);
    }

    // wave reduce, then tiny cross-wave reduce
    float sum = (s0 + s1) + (s2 + s3);
    float cnt = (float)((c0 + c1) + (c2 + c3));
    #pragma unroll
    for (int o = 32; o > 0; o >>= 1) {
        sum += __shfl_xor(sum, o);
        cnt += __shfl_xor(cnt, o);
    }

    __shared__ float rs[4], rc[4];
    const int wid = tid >> 6;
    if ((tid & 63) == 0) { rs[wid] = sum; rc[wid] = cnt; }
    __syncthreads();
    if (tid == 0) {
        psum[blockIdx.x] = (rs[0] + rs[1]) + (rs[2] + rs[3]);
        pcnt[blockIdx.x] = (rc[0] + rc[1]) + (rc[2] + rc[3]);
    }
}

// ---------------- Kernel C: final reduce + divide ----------------
__global__ __launch_bounds__(256) void finalize_kernel(
    const float* __restrict__ psum,
    const float* __restrict__ pcnt,
    float* __restrict__ out,
    int nblk)
{
    __shared__ double ss[256];
    __shared__ double sc[256];
    double s = 0.0, c = 0.0;
    for (int k = threadIdx.x; k < nblk; k += 256) {
        s += (double)psum[k];
        c += (double)pcnt[k];
    }
    ss[threadIdx.x] = s;
    sc[threadIdx.x] = c;
    __syncthreads();
    for (int st = 128; st > 0; st >>= 1) {
        if ((int)threadIdx.x < st) {
            ss[threadIdx.x] += ss[threadIdx.x + st];
            sc[threadIdx.x] += sc[threadIdx.x + st];
        }
        __syncthreads();
    }
    if (threadIdx.x == 0) {
        double cnt = sc[0] < 1.0 ? 1.0 : sc[0];
        out[0] = (float)(ss[0] / cnt);
    }
}

extern "C" void kernel_launch(void* const* d_in, const int* in_sizes, int n_in,
                              void* d_out, int out_size, void* d_ws, size_t ws_size,
                              hipStream_t stream)
{
    const float* energies = (const float*)d_in[0];  // (B,1) flat = B floats
    const float* pv       = (const float*)d_in[1];  // (B,P)
    const float* pt       = (const float*)d_in[2];  // (P,)
    int B = in_sizes[0];
    int P = in_sizes[2];

    int nblk = (B + NI - 1) / NI;    // 512 for B=8192 -> exactly 2 blocks/CU

    float* dist = (float*)d_ws;      // B floats
    float* psum = dist + B;          // nblk floats
    float* pcnt = psum + nblk;       // nblk floats

    dist_kernel<<<(B + 255) / 256, 256, 0, stream>>>(pv, pt, dist, B, P);
    pair_kernel<<<nblk, 256, 0, stream>>>(energies, dist, psum, pcnt, B);
    finalize_kernel<<<1, 256, 0, stream>>>(psum, pcnt, (float*)d_out, nblk);
}